// Round 4
// baseline (614.037 us; speedup 1.0000x reference)
//
#include <hip/hip_runtime.h>
#include <math.h>

static constexpr int BATCH = 2048;
// ws layout (floats):
//   P1 [128][512]: P1[i][s]  = maskedW1[unit(s)][i]          (input col i -> h1 slots)
//   P2 [512][512]: P2[sj][sk]= maskedW2[unit(sk)][unit(sj)]  (h1 slot -> h2 slots)
//   P3 [512][256]: P3[sj][o] = maskedW3[o][unit(sj)]         (h2 slot -> outputs)
static constexpr int P1_OFF = 0;
static constexpr int P2_OFF = 128 * 512;
static constexpr int P3_OFF = 128 * 512 + 512 * 512;
static constexpr int WS_FLOATS = P3_OFF + 512 * 256;

// slot s: i = s>>2, t = s&3; unit = (i==127) ? 508+t : 127*t + i.
// Degree-i units sit at slots 4i+t -> lane i&63, regs {t} (i<64) or {4+t} (i>=64).
__device__ __forceinline__ int unitOf(int s) {
    int i = s >> 2, t = s & 3;
    return (i == 127) ? (508 + t) : (127 * t + i);
}
__device__ __forceinline__ int degOf(int s) {
    int i = s >> 2;
    return (i == 127) ? (s & 3) : i;
}

__global__ __launch_bounds__(256) void maf_prep(
    const float* __restrict__ W1, const float* __restrict__ W2,
    const float* __restrict__ W3, float* __restrict__ ws)
{
    float* P1 = ws + P1_OFF;
    float* P2 = ws + P2_OFF;
    float* P3 = ws + P3_OFF;
    for (int idx = blockIdx.x * blockDim.x + threadIdx.x; idx < WS_FLOATS;
         idx += gridDim.x * blockDim.x) {
        if (idx < P2_OFF) {
            int i = idx >> 9, s = idx & 511;
            P1[idx] = (degOf(s) >= i) ? W1[unitOf(s) * 128 + i] : 0.f;
        } else if (idx < P3_OFF) {
            int e = idx - P2_OFF;
            int sj = e >> 9, sk = e & 511;
            P2[e] = (degOf(sk) >= degOf(sj)) ? W2[unitOf(sk) * 512 + unitOf(sj)] : 0.f;
        } else {
            int e = idx - P3_OFF;
            int sj = e >> 8, o = e & 255;
            int dd = (o & 127) - 1;  // degrees[3][o] = (o%128) - 1
            P3[e] = (dd >= degOf(sj)) ? W3[o * 512 + unitOf(sj)] : 0.f;
        }
    }
}

// Uniform-lane broadcast via v_readlane (VALU pipe; result is SGPR, usable
// directly as the scalar operand of v_fma).  No DS traffic.
__device__ __forceinline__ float rl(float v, int l) {
    return __int_as_float(__builtin_amdgcn_readlane(__float_as_int(v), l));
}
// Compile-time float4 component select (k constant after unroll).
__device__ __forceinline__ float fc(const float4& v, int k) {
    return k == 0 ? v.x : k == 1 ? v.y : k == 2 ? v.z : v.w;
}

// Per-step weight register set:
//   v[0]=P1 lo, v[1]=P1 hi, v[2+2t]=P2 t lo, v[3+2t]=P2 t hi, v[10+t]=P3 t.
struct WSet { float4 v[14]; };

__global__ __launch_bounds__(256, 1) void maf_inverse(
    const float* __restrict__ u, const float* __restrict__ b1,
    const float* __restrict__ b2, const float* __restrict__ b3,
    const float* __restrict__ ws, float* __restrict__ out)
{
    const float* P1 = ws + P1_OFF;
    const float* P2 = ws + P2_OFF;
    const float* P3 = ws + P3_OFF;

    const int td = threadIdx.x;
    const int lane = td & 63;
    const int wid = td >> 6;
    const int rA = blockIdx.x * 8 + wid * 2;
    const int rB = rA + 1;

    // register state: h slots {4*lane+r} (lo) and {256+4*lane+r} (hi); z outputs 4*lane+s.
    float h1A[8], h1B[8], h2A[8], h2B[8];
#pragma unroll
    for (int r = 0; r < 8; ++r) {
        int s = (r < 4) ? (4 * lane + r) : (256 + 4 * lane + (r - 4));
        int uu = unitOf(s);
        float v1 = b1[uu], v2 = b2[uu];
        h1A[r] = v1; h1B[r] = v1; h2A[r] = v2; h2B[r] = v2;
    }
    float zA[4], zB[4];
    {
        const float4 bz = *(const float4*)(b3 + 4 * lane);
        zA[0] = bz.x; zA[1] = bz.y; zA[2] = bz.z; zA[3] = bz.w;
        zB[0] = bz.x; zB[1] = bz.y; zB[2] = bz.z; zB[3] = bz.w;
    }
    const float uA0 = u[rA * 128 + lane], uA1 = u[rA * 128 + 64 + lane];
    const float uB0 = u[rB * 128 + lane], uB1 = u[rB * 128 + 64 + lane];

    float xA0 = 0.f, xA1 = 0.f, xB0 = 0.f, xB1 = 0.f, ldA = 0.f, ldB = 0.f;

    // running per-thread column pointers (advance once per loaded step)
    const float* q1  = P1 + 4 * lane;
    const float* q2a = P2 + 4 * lane;
    const float* q2b = P2 + 1024 + 4 * lane;
    const float* q3  = P3 + 4 * lane;

    WSet wa, wb;

    auto loads = [&](WSet& w, bool lo) {
        if (lo) w.v[0] = *(const float4*)(q1);
        w.v[1] = *(const float4*)(q1 + 256);
        if (lo) {
            w.v[2] = *(const float4*)(q2a);
            w.v[4] = *(const float4*)(q2a + 512);
            w.v[6] = *(const float4*)(q2b);
            w.v[8] = *(const float4*)(q2b + 512);
        }
        w.v[3] = *(const float4*)(q2a + 256);
        w.v[5] = *(const float4*)(q2a + 768);
        w.v[7] = *(const float4*)(q2b + 256);
        w.v[9] = *(const float4*)(q2b + 768);
        w.v[10] = *(const float4*)(q3);
        w.v[11] = *(const float4*)(q3 + 256);
        w.v[12] = *(const float4*)(q3 + 512);
        w.v[13] = *(const float4*)(q3 + 768);
        q1 += 512; q2a += 2048; q2b += 2048; q3 += 1024;
    };

    auto step = [&](int i, const WSet& w) {
        const bool lo = i < 64;
        const int l0 = i & 63, lm = i >> 2, rs = i & 3;
        // x_i = u_i * exp(sigma_i) + mu_i   (mu at output i -> lane i>>2 comp i&3;
        //                                    sigma at 128+i -> lane 32+(i>>2))
        float zsA = rs == 0 ? zA[0] : rs == 1 ? zA[1] : rs == 2 ? zA[2] : zA[3];
        float zsB = rs == 0 ? zB[0] : rs == 1 ? zB[1] : rs == 2 ? zB[2] : zB[3];
        const float muA = rl(zsA, lm), sgA = rl(zsA, 32 + lm);
        const float muB = rl(zsB, lm), sgB = rl(zsB, 32 + lm);
        const float uiA = rl(lo ? uA0 : uA1, l0);
        const float uiB = rl(lo ? uB0 : uB1, l0);
        const float xiA = fmaf(uiA, __expf(sgA), muA);
        const float xiB = fmaf(uiB, __expf(sgB), muB);
        ldA += sgA; ldB += sgB;
        if (lane == l0) {
            if (lo) { xA0 = xiA; xB0 = xiB; } else { xA1 = xiA; xB1 = xiB; }
        }
        // L1: scatter x_i (slots with deg<i hold zeros; lo half all-zero for i>=64)
        if (lo) {
#pragma unroll
            for (int r = 0; r < 4; ++r) {
                h1A[r] = fmaf(fc(w.v[0], r), xiA, h1A[r]);
                h1B[r] = fmaf(fc(w.v[0], r), xiB, h1B[r]);
            }
        }
#pragma unroll
        for (int r = 0; r < 4; ++r) {
            h1A[4 + r] = fmaf(fc(w.v[1], r), xiA, h1A[4 + r]);
            h1B[4 + r] = fmaf(fc(w.v[1], r), xiB, h1B[4 + r]);
        }
        // L2: propagate the 4 regular h1 units of degree i (slots 4i+t)
#pragma unroll
        for (int t = 0; t < 4; ++t) {
            float aS = lo ? h1A[t] : h1A[4 + t];
            float bS = lo ? h1B[t] : h1B[4 + t];
            const float hA = rl(fmaxf(aS, 0.f), l0);
            const float hB = rl(fmaxf(bS, 0.f), l0);
            if (lo) {
#pragma unroll
                for (int r = 0; r < 4; ++r) {
                    h2A[r] = fmaf(fc(w.v[2 + 2 * t], r), hA, h2A[r]);
                    h2B[r] = fmaf(fc(w.v[2 + 2 * t], r), hB, h2B[r]);
                }
            }
#pragma unroll
            for (int r = 0; r < 4; ++r) {
                h2A[4 + r] = fmaf(fc(w.v[3 + 2 * t], r), hA, h2A[4 + r]);
                h2B[4 + r] = fmaf(fc(w.v[3 + 2 * t], r), hB, h2B[4 + r]);
            }
        }
        if (i < 4) {  // extra h1 unit 508+i (slot 508+i -> lane 63, reg 4+i)
            float eA = i == 0 ? h1A[4] : i == 1 ? h1A[5] : i == 2 ? h1A[6] : h1A[7];
            float eB = i == 0 ? h1B[4] : i == 1 ? h1B[5] : i == 2 ? h1B[6] : h1B[7];
            const float hA = rl(fmaxf(eA, 0.f), 63);
            const float hB = rl(fmaxf(eB, 0.f), 63);
            const float* wr = P2 + (508 + i) * 512 + 4 * lane;
            const float4 wl = *(const float4*)(wr);
            const float4 wh = *(const float4*)(wr + 256);
#pragma unroll
            for (int r = 0; r < 4; ++r) {
                h2A[r] = fmaf(fc(wl, r), hA, h2A[r]);
                h2B[r] = fmaf(fc(wl, r), hB, h2B[r]);
                h2A[4 + r] = fmaf(fc(wh, r), hA, h2A[4 + r]);
                h2B[4 + r] = fmaf(fc(wh, r), hB, h2B[4 + r]);
            }
        }
        // L3: propagate the 4 regular h2 units of degree i
#pragma unroll
        for (int t = 0; t < 4; ++t) {
            float aS = lo ? h2A[t] : h2A[4 + t];
            float bS = lo ? h2B[t] : h2B[4 + t];
            const float gA = rl(fmaxf(aS, 0.f), l0);
            const float gB = rl(fmaxf(bS, 0.f), l0);
#pragma unroll
            for (int s = 0; s < 4; ++s) {
                zA[s] = fmaf(fc(w.v[10 + t], s), gA, zA[s]);
                zB[s] = fmaf(fc(w.v[10 + t], s), gB, zB[s]);
            }
        }
        if (i < 4) {  // extra h2 unit 508+i
            float eA = i == 0 ? h2A[4] : i == 1 ? h2A[5] : i == 2 ? h2A[6] : h2A[7];
            float eB = i == 0 ? h2B[4] : i == 1 ? h2B[5] : i == 2 ? h2B[6] : h2B[7];
            const float gA = rl(fmaxf(eA, 0.f), 63);
            const float gB = rl(fmaxf(eB, 0.f), 63);
            const float4 w4 = *(const float4*)(P3 + (508 + i) * 256 + 4 * lane);
#pragma unroll
            for (int s = 0; s < 4; ++s) {
                zA[s] = fmaf(fc(w4, s), gA, zA[s]);
                zB[s] = fmaf(fc(w4, s), gB, zB[s]);
            }
        }
    };

    loads(wa, true);  // step 0
#pragma unroll 1
    for (int i = 0; i < 126; i += 2) {
        loads(wb, (i + 1) < 64);   // prefetch step i+1 while computing step i
        step(i, wa);
        loads(wa, (i + 2) < 64);   // prefetch step i+2 while computing step i+1
        step(i + 1, wb);
    }
    step(126, wa);

    // step 127: no propagation, just x_127 and logdet (lm=31, rs=3, l0=63)
    {
        const float muA = rl(zA[3], 31), sgA = rl(zA[3], 63);
        const float muB = rl(zB[3], 31), sgB = rl(zB[3], 63);
        const float uiA = rl(uA1, 63), uiB = rl(uB1, 63);
        const float xiA = fmaf(uiA, __expf(sgA), muA);
        const float xiB = fmaf(uiB, __expf(sgB), muB);
        ldA += sgA; ldB += sgB;
        if (lane == 63) { xA1 = xiA; xB1 = xiB; }
    }

    out[rA * 128 + lane] = xA0;
    out[rA * 128 + 64 + lane] = xA1;
    out[rB * 128 + lane] = xB0;
    out[rB * 128 + 64 + lane] = xB1;
    if (lane == 0) {
        out[BATCH * 128 + rA] = ldA;
        out[BATCH * 128 + rB] = ldB;
    }
}

extern "C" void kernel_launch(void* const* d_in, const int* in_sizes, int n_in,
                              void* d_out, int out_size, void* d_ws, size_t ws_size,
                              hipStream_t stream)
{
    const float* u  = (const float*)d_in[0];
    const float* W1 = (const float*)d_in[1];
    const float* b1 = (const float*)d_in[2];
    const float* W2 = (const float*)d_in[3];
    const float* b2 = (const float*)d_in[4];
    const float* W3 = (const float*)d_in[5];
    const float* b3 = (const float*)d_in[6];
    // masks computed analytically in maf_prep; d_in[7..9] unused.
    float* ws  = (float*)d_ws;
    float* out = (float*)d_out;
    (void)ws_size; (void)in_sizes; (void)n_in; (void)out_size;

    maf_prep<<<512, 256, 0, stream>>>(W1, W2, W3, ws);
    maf_inverse<<<256, 256, 0, stream>>>(u, b1, b2, b3, ws, out);
}

// Round 5
// 161.216 us; speedup vs baseline: 3.8088x; 3.8088x over previous
//
#include <hip/hip_runtime.h>
#include <math.h>

static constexpr int BATCH = 2048;
// ws layout (floats):
//   P1 [128][512]: P1[i][s]  = maskedW1[unit(s)][i]          (input col i -> h1 slots)
//   P2 [512][512]: P2[sj][sk]= maskedW2[unit(sk)][unit(sj)]  (h1 slot -> h2 slots)
//   P3 [512][256]: P3[sj][o] = maskedW3[o][unit(sj)]         (h2 slot -> outputs)
static constexpr int P1_OFF = 0;
static constexpr int P2_OFF = 128 * 512;
static constexpr int P3_OFF = 128 * 512 + 512 * 512;

// unit j -> slot s: s = 4*(j%127) + j/127 for j<508, s=j for j>=508.
// slot s=4i+t -> unit 127t+i (i<127), unit 508+t (i=127). deg(unit j) = j%127.
// Degree-i units sit at slots 4i+t -> lane i&63, regs {t} (i<64) or {4+t} (i>=64).

__device__ __forceinline__ float fc(float4 v, int k) {
    return k == 0 ? v.x : k == 1 ? v.y : k == 2 ? v.z : v.w;
}
// Uniform-lane broadcast via v_readlane (VALU pipe, SGPR result).
__device__ __forceinline__ float rl(float v, int l) {
    return __int_as_float(__builtin_amdgcn_readlane(__float_as_int(v), l));
}

// ---------------------------------------------------------------------------
// Prep: coalesced float4 READS along W rows, scattered 4B writes into the
// permuted layouts (reads stall, writes don't).
// ---------------------------------------------------------------------------
__global__ __launch_bounds__(256) void maf_prep(
    const float* __restrict__ W1, const float* __restrict__ W2,
    const float* __restrict__ W3, float* __restrict__ ws)
{
    float* P1 = ws + P1_OFF;
    float* P2 = ws + P2_OFF;
    float* P3 = ws + P3_OFF;
    const int NQ1 = 512 * 128 / 4;   // 16384
    const int NQ2 = 512 * 512 / 4;   // 65536
    const int NQ3 = 256 * 512 / 4;   // 32768
    for (int q = blockIdx.x * blockDim.x + threadIdx.x; q < NQ1 + NQ2 + NQ3;
         q += gridDim.x * blockDim.x) {
        if (q < NQ1) {
            int j = q >> 5, i0 = (q & 31) * 4;
            float4 v = *(const float4*)(W1 + j * 128 + i0);
            int dj = j % 127;
            int sj = (j < 508) ? 4 * dj + (j / 127) : j;
#pragma unroll
            for (int c = 0; c < 4; ++c) {
                int i = i0 + c;
                P1[i * 512 + sj] = (dj >= i) ? fc(v, c) : 0.f;
            }
        } else if (q < NQ1 + NQ2) {
            int e = q - NQ1;
            int k = e >> 7, j0 = (e & 127) * 4;
            float4 v = *(const float4*)(W2 + k * 512 + j0);
            int dk = k % 127;
            int sk = (k < 508) ? 4 * dk + (k / 127) : k;
#pragma unroll
            for (int c = 0; c < 4; ++c) {
                int j = j0 + c;
                int dj = j % 127;
                int sj = (j < 508) ? 4 * dj + (j / 127) : j;
                P2[sj * 512 + sk] = (dk >= dj) ? fc(v, c) : 0.f;
            }
        } else {
            int e = q - NQ1 - NQ2;
            int o = e >> 7, k0 = (e & 127) * 4;
            float4 v = *(const float4*)(W3 + o * 512 + k0);
            int dd = (o & 127) - 1;   // degrees[3][o] = (o%128) - 1
#pragma unroll
            for (int c = 0; c < 4; ++c) {
                int k = k0 + c;
                int dk = k % 127;
                int sk = (k < 508) ? 4 * dk + (k / 127) : k;
                P3[sk * 256 + o] = (dd >= dk) ? fc(v, c) : 0.f;
            }
        }
    }
}

// ---------------------------------------------------------------------------
// Weight double-buffer: 28 NAMED float4 registers (no arrays, no structs —
// nothing the spill/promote passes can demote; round-4 lesson, rule #20).
//   P##0  = P1 col lo     P##1  = P1 col hi
//   P##(2+2t) = P2 row t lo   P##(3+2t) = P2 row t hi   (t = 0..3)
//   P##(10+t) = P3 row t                                 (t = 0..3)
// ---------------------------------------------------------------------------
#define DECL_WSET(P) \
    float4 P##0, P##1, P##2, P##3, P##4, P##5, P##6, P##7, P##8, P##9, \
           P##10, P##11, P##12, P##13;

#define LOADS(P, LO) do { \
    if (LO) { \
        P##0 = *(const float4*)(q1); \
        P##2 = *(const float4*)(q2a); \
        P##4 = *(const float4*)(q2a + 512); \
        P##6 = *(const float4*)(q2b); \
        P##8 = *(const float4*)(q2b + 512); \
    } \
    P##1  = *(const float4*)(q1 + 256); \
    P##3  = *(const float4*)(q2a + 256); \
    P##5  = *(const float4*)(q2a + 768); \
    P##7  = *(const float4*)(q2b + 256); \
    P##9  = *(const float4*)(q2b + 768); \
    P##10 = *(const float4*)(q3); \
    P##11 = *(const float4*)(q3 + 256); \
    P##12 = *(const float4*)(q3 + 512); \
    P##13 = *(const float4*)(q3 + 768); \
    q1 += 512; q2a += 2048; q2b += 2048; q3 += 1024; \
} while (0)

#define L2T(T, WLO, WHI) do { \
    float aS = lo ? h1A[T] : h1A[4 + (T)]; \
    float bS = lo ? h1B[T] : h1B[4 + (T)]; \
    const float hA = rl(fmaxf(aS, 0.f), l0); \
    const float hB = rl(fmaxf(bS, 0.f), l0); \
    if (lo) { \
        _Pragma("unroll") for (int r = 0; r < 4; ++r) { \
            h2A[r] = fmaf(fc(WLO, r), hA, h2A[r]); \
            h2B[r] = fmaf(fc(WLO, r), hB, h2B[r]); } \
    } \
    _Pragma("unroll") for (int r = 0; r < 4; ++r) { \
        h2A[4 + r] = fmaf(fc(WHI, r), hA, h2A[4 + r]); \
        h2B[4 + r] = fmaf(fc(WHI, r), hB, h2B[4 + r]); } \
} while (0)

#define L3T(T, W4) do { \
    float aS = lo ? h2A[T] : h2A[4 + (T)]; \
    float bS = lo ? h2B[T] : h2B[4 + (T)]; \
    const float gA = rl(fmaxf(aS, 0.f), l0); \
    const float gB = rl(fmaxf(bS, 0.f), l0); \
    _Pragma("unroll") for (int s = 0; s < 4; ++s) { \
        zA[s] = fmaf(fc(W4, s), gA, zA[s]); \
        zB[s] = fmaf(fc(W4, s), gB, zB[s]); } \
} while (0)

#define STEP(I, P) do { \
    const bool lo = (I) < 64; \
    const int l0 = (I) & 63, lm = (I) >> 2, rs = (I) & 3; \
    float zsA = rs == 0 ? zA[0] : rs == 1 ? zA[1] : rs == 2 ? zA[2] : zA[3]; \
    float zsB = rs == 0 ? zB[0] : rs == 1 ? zB[1] : rs == 2 ? zB[2] : zB[3]; \
    const float muA = rl(zsA, lm), sgA = rl(zsA, 32 + lm); \
    const float muB = rl(zsB, lm), sgB = rl(zsB, 32 + lm); \
    const float uiA = rl(lo ? uA0 : uA1, l0); \
    const float uiB = rl(lo ? uB0 : uB1, l0); \
    const float xiA = fmaf(uiA, __expf(sgA), muA); \
    const float xiB = fmaf(uiB, __expf(sgB), muB); \
    ldA += sgA; ldB += sgB; \
    if (lane == l0) { \
        if (lo) { xA0 = xiA; xB0 = xiB; } else { xA1 = xiA; xB1 = xiB; } \
    } \
    if (lo) { \
        _Pragma("unroll") for (int r = 0; r < 4; ++r) { \
            h1A[r] = fmaf(fc(P##0, r), xiA, h1A[r]); \
            h1B[r] = fmaf(fc(P##0, r), xiB, h1B[r]); } \
    } \
    _Pragma("unroll") for (int r = 0; r < 4; ++r) { \
        h1A[4 + r] = fmaf(fc(P##1, r), xiA, h1A[4 + r]); \
        h1B[4 + r] = fmaf(fc(P##1, r), xiB, h1B[4 + r]); } \
    L2T(0, P##2, P##3); \
    L2T(1, P##4, P##5); \
    L2T(2, P##6, P##7); \
    L2T(3, P##8, P##9); \
    if ((I) < 4) { \
        float eA = (I) == 0 ? h1A[4] : (I) == 1 ? h1A[5] : (I) == 2 ? h1A[6] : h1A[7]; \
        float eB = (I) == 0 ? h1B[4] : (I) == 1 ? h1B[5] : (I) == 2 ? h1B[6] : h1B[7]; \
        const float hA = rl(fmaxf(eA, 0.f), 63); \
        const float hB = rl(fmaxf(eB, 0.f), 63); \
        const float* wr = P2 + (508 + (I)) * 512 + 4 * lane; \
        const float4 wl = *(const float4*)(wr); \
        const float4 wh = *(const float4*)(wr + 256); \
        _Pragma("unroll") for (int r = 0; r < 4; ++r) { \
            h2A[r] = fmaf(fc(wl, r), hA, h2A[r]); \
            h2B[r] = fmaf(fc(wl, r), hB, h2B[r]); \
            h2A[4 + r] = fmaf(fc(wh, r), hA, h2A[4 + r]); \
            h2B[4 + r] = fmaf(fc(wh, r), hB, h2B[4 + r]); } \
    } \
    L3T(0, P##10); \
    L3T(1, P##11); \
    L3T(2, P##12); \
    L3T(3, P##13); \
    if ((I) < 4) { \
        float eA = (I) == 0 ? h2A[4] : (I) == 1 ? h2A[5] : (I) == 2 ? h2A[6] : h2A[7]; \
        float eB = (I) == 0 ? h2B[4] : (I) == 1 ? h2B[5] : (I) == 2 ? h2B[6] : h2B[7]; \
        const float gA = rl(fmaxf(eA, 0.f), 63); \
        const float gB = rl(fmaxf(eB, 0.f), 63); \
        const float4 w4 = *(const float4*)(P3 + (508 + (I)) * 256 + 4 * lane); \
        _Pragma("unroll") for (int s = 0; s < 4; ++s) { \
            zA[s] = fmaf(fc(w4, s), gA, zA[s]); \
            zB[s] = fmaf(fc(w4, s), gB, zB[s]); } \
    } \
} while (0)

__global__ __launch_bounds__(256, 1) void maf_inverse(
    const float* __restrict__ u, const float* __restrict__ b1,
    const float* __restrict__ b2, const float* __restrict__ b3,
    const float* __restrict__ ws, float* __restrict__ out)
{
    const float* P1 = ws + P1_OFF;
    const float* P2 = ws + P2_OFF;
    const float* P3 = ws + P3_OFF;

    const int td = threadIdx.x;
    const int lane = td & 63;
    const int wid = td >> 6;
    const int rA = blockIdx.x * 8 + wid * 2;
    const int rB = rA + 1;

    // state: h slots {4*lane+r} (regs 0..3) and {256+4*lane+r} (regs 4..7);
    // z outputs {4*lane+s}.
    float h1A[8], h1B[8], h2A[8], h2B[8];
#pragma unroll
    for (int r = 0; r < 8; ++r) {
        int s = (r < 4) ? (4 * lane + r) : (256 + 4 * lane + (r - 4));
        int i = s >> 2, t = s & 3;
        int uu = (i == 127) ? (508 + t) : (127 * t + i);
        float v1 = b1[uu], v2 = b2[uu];
        h1A[r] = v1; h1B[r] = v1; h2A[r] = v2; h2B[r] = v2;
    }
    float zA[4], zB[4];
    {
        const float4 bz = *(const float4*)(b3 + 4 * lane);
        zA[0] = bz.x; zA[1] = bz.y; zA[2] = bz.z; zA[3] = bz.w;
        zB[0] = bz.x; zB[1] = bz.y; zB[2] = bz.z; zB[3] = bz.w;
    }
    const float uA0 = u[rA * 128 + lane], uA1 = u[rA * 128 + 64 + lane];
    const float uB0 = u[rB * 128 + lane], uB1 = u[rB * 128 + 64 + lane];

    float xA0 = 0.f, xA1 = 0.f, xB0 = 0.f, xB1 = 0.f, ldA = 0.f, ldB = 0.f;

    // running per-thread column pointers (advance once per LOADS)
    const float* q1  = P1 + 4 * lane;
    const float* q2a = P2 + 4 * lane;
    const float* q2b = P2 + 1024 + 4 * lane;
    const float* q3  = P3 + 4 * lane;

    DECL_WSET(wa)
    DECL_WSET(wb)

    LOADS(wa, true);   // step 0
#pragma unroll 1
    for (int i = 0; i < 126; i += 2) {
        LOADS(wb, (i + 1) < 64);   // prefetch step i+1 under step i's compute
        STEP(i, wa);
        LOADS(wa, (i + 2) < 64);   // prefetch step i+2 under step i+1
        STEP(i + 1, wb);
    }
    STEP(126, wa);

    // step 127: no propagation — x_127 and logdet only (mu=z[127], sg=z[255])
    {
        const float muA = rl(zA[3], 31), sgA = rl(zA[3], 63);
        const float muB = rl(zB[3], 31), sgB = rl(zB[3], 63);
        const float uiA = rl(uA1, 63), uiB = rl(uB1, 63);
        const float xiA = fmaf(uiA, __expf(sgA), muA);
        const float xiB = fmaf(uiB, __expf(sgB), muB);
        ldA += sgA; ldB += sgB;
        if (lane == 63) { xA1 = xiA; xB1 = xiB; }
    }

    out[rA * 128 + lane]      = xA0;
    out[rA * 128 + 64 + lane] = xA1;
    out[rB * 128 + lane]      = xB0;
    out[rB * 128 + 64 + lane] = xB1;
    if (lane == 0) {
        out[BATCH * 128 + rA] = ldA;
        out[BATCH * 128 + rB] = ldB;
    }
}

extern "C" void kernel_launch(void* const* d_in, const int* in_sizes, int n_in,
                              void* d_out, int out_size, void* d_ws, size_t ws_size,
                              hipStream_t stream)
{
    const float* u  = (const float*)d_in[0];
    const float* W1 = (const float*)d_in[1];
    const float* b1 = (const float*)d_in[2];
    const float* W2 = (const float*)d_in[3];
    const float* b2 = (const float*)d_in[4];
    const float* W3 = (const float*)d_in[5];
    const float* b3 = (const float*)d_in[6];
    // masks computed analytically in maf_prep; d_in[7..9] unused.
    float* ws  = (float*)d_ws;
    float* out = (float*)d_out;
    (void)ws_size; (void)in_sizes; (void)n_in; (void)out_size;

    maf_prep<<<448, 256, 0, stream>>>(W1, W2, W3, ws);
    maf_inverse<<<256, 256, 0, stream>>>(u, b1, b2, b3, ws, out);
}

// Round 6
// 139.074 us; speedup vs baseline: 4.4152x; 1.1592x over previous
//
#include <hip/hip_runtime.h>
#include <math.h>

static constexpr int BATCH = 2048;
// ws layout (floats):
//   P1 [128][512]: P1[i][s]  = maskedW1[unit(s)][i]          (input col i -> h1 slots)
//   P2 [512][512]: P2[sj][sk]= maskedW2[unit(sk)][unit(sj)]  (h1 slot -> h2 slots)
//   P3 [512][256]: P3[sj][o] = maskedW3[o][unit(sj)]         (h2 slot -> outputs)
static constexpr int P1_OFF = 0;
static constexpr int P2_OFF = 128 * 512;
static constexpr int P3_OFF = 128 * 512 + 512 * 512;

// unit j -> slot s: s = 4*(j%127) + j/127 for j<508, s=j for j>=508.
// slot s=4i+t -> unit 127t+i (i<127), unit 508+t (i=127). deg(unit j) = j%127.
// Degree-i units sit at slots 4i+t -> lane i&63, regs {t} (i<64) or {4+t} (i>=64).

__device__ __forceinline__ float fc(float4 v, int k) {
    return k == 0 ? v.x : k == 1 ? v.y : k == 2 ? v.z : v.w;
}
// Uniform-lane broadcast via v_readlane (VALU pipe, SGPR result).
__device__ __forceinline__ float rl(float v, int l) {
    return __int_as_float(__builtin_amdgcn_readlane(__float_as_int(v), l));
}

// ---------------------------------------------------------------------------
// Prep: coalesced float4 READS along W rows, scattered 4B writes into the
// permuted layouts (reads stall, writes don't).
// ---------------------------------------------------------------------------
__global__ __launch_bounds__(256) void maf_prep(
    const float* __restrict__ W1, const float* __restrict__ W2,
    const float* __restrict__ W3, float* __restrict__ ws)
{
    float* P1 = ws + P1_OFF;
    float* P2 = ws + P2_OFF;
    float* P3 = ws + P3_OFF;
    const int NQ1 = 512 * 128 / 4;   // 16384
    const int NQ2 = 512 * 512 / 4;   // 65536
    const int NQ3 = 256 * 512 / 4;   // 32768
    for (int q = blockIdx.x * blockDim.x + threadIdx.x; q < NQ1 + NQ2 + NQ3;
         q += gridDim.x * blockDim.x) {
        if (q < NQ1) {
            int j = q >> 5, i0 = (q & 31) * 4;
            float4 v = *(const float4*)(W1 + j * 128 + i0);
            int dj = j % 127;
            int sj = (j < 508) ? 4 * dj + (j / 127) : j;
#pragma unroll
            for (int c = 0; c < 4; ++c) {
                int i = i0 + c;
                P1[i * 512 + sj] = (dj >= i) ? fc(v, c) : 0.f;
            }
        } else if (q < NQ1 + NQ2) {
            int e = q - NQ1;
            int k = e >> 7, j0 = (e & 127) * 4;
            float4 v = *(const float4*)(W2 + k * 512 + j0);
            int dk = k % 127;
            int sk = (k < 508) ? 4 * dk + (k / 127) : k;
#pragma unroll
            for (int c = 0; c < 4; ++c) {
                int j = j0 + c;
                int dj = j % 127;
                int sj = (j < 508) ? 4 * dj + (j / 127) : j;
                P2[sj * 512 + sk] = (dk >= dj) ? fc(v, c) : 0.f;
            }
        } else {
            int e = q - NQ1 - NQ2;
            int o = e >> 7, k0 = (e & 127) * 4;
            float4 v = *(const float4*)(W3 + o * 512 + k0);
            int dd = (o & 127) - 1;   // degrees[3][o] = (o%128) - 1
#pragma unroll
            for (int c = 0; c < 4; ++c) {
                int k = k0 + c;
                int dk = k % 127;
                int sk = (k < 508) ? 4 * dk + (k / 127) : k;
                P3[sk * 256 + o] = (dd >= dk) ? fc(v, c) : 0.f;
            }
        }
    }
}

// ---------------------------------------------------------------------------
// Weight double-buffer: 28 NAMED float4 registers.  LOADS is followed by a
// sched_barrier(0) at each call site so the loads cannot be sunk into the
// consuming STEP (round-5 lesson: without the pin, the compiler re-folds the
// pipeline into just-in-time loads; VGPR count dropped to 92 and every step
// stalled on L2 latency).
//   P##0  = P1 col lo     P##1  = P1 col hi
//   P##(2+2t) = P2 row t lo   P##(3+2t) = P2 row t hi   (t = 0..3)
//   P##(10+t) = P3 row t                                 (t = 0..3)
// ---------------------------------------------------------------------------
#define DECL_WSET(P) \
    float4 P##0{}, P##1{}, P##2{}, P##3{}, P##4{}, P##5{}, P##6{}, P##7{}, \
           P##8{}, P##9{}, P##10{}, P##11{}, P##12{}, P##13{};

#define LOADS(P, LO) do { \
    if (LO) { \
        P##0 = *(const float4*)(q1); \
        P##2 = *(const float4*)(q2a); \
        P##4 = *(const float4*)(q2a + 512); \
        P##6 = *(const float4*)(q2b); \
        P##8 = *(const float4*)(q2b + 512); \
    } \
    P##1  = *(const float4*)(q1 + 256); \
    P##3  = *(const float4*)(q2a + 256); \
    P##5  = *(const float4*)(q2a + 768); \
    P##7  = *(const float4*)(q2b + 256); \
    P##9  = *(const float4*)(q2b + 768); \
    P##10 = *(const float4*)(q3); \
    P##11 = *(const float4*)(q3 + 256); \
    P##12 = *(const float4*)(q3 + 512); \
    P##13 = *(const float4*)(q3 + 768); \
    q1 += 512; q2a += 2048; q2b += 2048; q3 += 1024; \
    __builtin_amdgcn_sched_barrier(0); \
} while (0)

// T-th regular unit of degree I: broadcast relu from static reg, FMA into h2.
#define L2T(T, WLO, WHI, LO) do { \
    const float hA = rl(fmaxf(LO ? h1A[T] : h1A[4 + (T)], 0.f), l0); \
    const float hB = rl(fmaxf(LO ? h1B[T] : h1B[4 + (T)], 0.f), l0); \
    if (LO) { \
        _Pragma("unroll") for (int r = 0; r < 4; ++r) { \
            h2A[r] = fmaf(fc(WLO, r), hA, h2A[r]); \
            h2B[r] = fmaf(fc(WLO, r), hB, h2B[r]); } \
    } \
    _Pragma("unroll") for (int r = 0; r < 4; ++r) { \
        h2A[4 + r] = fmaf(fc(WHI, r), hA, h2A[4 + r]); \
        h2B[4 + r] = fmaf(fc(WHI, r), hB, h2B[4 + r]); } \
} while (0)

#define L3T(T, W4, LO) do { \
    const float gA = rl(fmaxf(LO ? h2A[T] : h2A[4 + (T)], 0.f), l0); \
    const float gB = rl(fmaxf(LO ? h2B[T] : h2B[4 + (T)], 0.f), l0); \
    _Pragma("unroll") for (int s = 0; s < 4; ++s) { \
        zA[s] = fmaf(fc(W4, s), gA, zA[s]); \
        zB[s] = fmaf(fc(W4, s), gB, zB[s]); } \
} while (0)

// One inversion step.  I may be runtime; LO must be a compile-time literal
// matching (I) < 64 so all predicates fold.
#define STEP(I, P, LO) do { \
    const int l0 = (I) & 63, lm = (I) >> 2, rs = (I) & 3; \
    float zsA = rs == 0 ? zA[0] : rs == 1 ? zA[1] : rs == 2 ? zA[2] : zA[3]; \
    float zsB = rs == 0 ? zB[0] : rs == 1 ? zB[1] : rs == 2 ? zB[2] : zB[3]; \
    const float muA = rl(zsA, lm), sgA = rl(zsA, 32 + lm); \
    const float muB = rl(zsB, lm), sgB = rl(zsB, 32 + lm); \
    const float uiA = rl(LO ? uA0 : uA1, l0); \
    const float uiB = rl(LO ? uB0 : uB1, l0); \
    const float xiA = fmaf(uiA, __expf(sgA), muA); \
    const float xiB = fmaf(uiB, __expf(sgB), muB); \
    ldA += sgA; ldB += sgB; \
    if (lane == l0) { \
        if (LO) { xA0 = xiA; xB0 = xiB; } else { xA1 = xiA; xB1 = xiB; } \
    } \
    if (LO) { \
        _Pragma("unroll") for (int r = 0; r < 4; ++r) { \
            h1A[r] = fmaf(fc(P##0, r), xiA, h1A[r]); \
            h1B[r] = fmaf(fc(P##0, r), xiB, h1B[r]); } \
    } \
    _Pragma("unroll") for (int r = 0; r < 4; ++r) { \
        h1A[4 + r] = fmaf(fc(P##1, r), xiA, h1A[4 + r]); \
        h1B[4 + r] = fmaf(fc(P##1, r), xiB, h1B[4 + r]); } \
    L2T(0, P##2, P##3, LO); \
    L2T(1, P##4, P##5, LO); \
    L2T(2, P##6, P##7, LO); \
    L2T(3, P##8, P##9, LO); \
    if (LO && (I) < 4) { \
        float eA = (I) == 0 ? h1A[4] : (I) == 1 ? h1A[5] : (I) == 2 ? h1A[6] : h1A[7]; \
        float eB = (I) == 0 ? h1B[4] : (I) == 1 ? h1B[5] : (I) == 2 ? h1B[6] : h1B[7]; \
        const float hA = rl(fmaxf(eA, 0.f), 63); \
        const float hB = rl(fmaxf(eB, 0.f), 63); \
        const float* wr = P2 + (508 + (I)) * 512 + 4 * lane; \
        const float4 wl = *(const float4*)(wr); \
        const float4 wh = *(const float4*)(wr + 256); \
        _Pragma("unroll") for (int r = 0; r < 4; ++r) { \
            h2A[r] = fmaf(fc(wl, r), hA, h2A[r]); \
            h2B[r] = fmaf(fc(wl, r), hB, h2B[r]); \
            h2A[4 + r] = fmaf(fc(wh, r), hA, h2A[4 + r]); \
            h2B[4 + r] = fmaf(fc(wh, r), hB, h2B[4 + r]); } \
    } \
    L3T(0, P##10, LO); \
    L3T(1, P##11, LO); \
    L3T(2, P##12, LO); \
    L3T(3, P##13, LO); \
    if (LO && (I) < 4) { \
        float eA = (I) == 0 ? h2A[4] : (I) == 1 ? h2A[5] : (I) == 2 ? h2A[6] : h2A[7]; \
        float eB = (I) == 0 ? h2B[4] : (I) == 1 ? h2B[5] : (I) == 2 ? h2B[6] : h2B[7]; \
        const float gA = rl(fmaxf(eA, 0.f), 63); \
        const float gB = rl(fmaxf(eB, 0.f), 63); \
        const float4 w4 = *(const float4*)(P3 + (508 + (I)) * 256 + 4 * lane); \
        _Pragma("unroll") for (int s = 0; s < 4; ++s) { \
            zA[s] = fmaf(fc(w4, s), gA, zA[s]); \
            zB[s] = fmaf(fc(w4, s), gB, zB[s]); } \
    } \
} while (0)

__global__ __launch_bounds__(256, 1) void maf_inverse(
    const float* __restrict__ u, const float* __restrict__ b1,
    const float* __restrict__ b2, const float* __restrict__ b3,
    const float* __restrict__ ws, float* __restrict__ out)
{
    const float* P1 = ws + P1_OFF;
    const float* P2 = ws + P2_OFF;
    const float* P3 = ws + P3_OFF;

    const int td = threadIdx.x;
    const int lane = td & 63;
    const int wid = td >> 6;
    const int rA = blockIdx.x * 8 + wid * 2;
    const int rB = rA + 1;

    // state: h slots {4*lane+r} (regs 0..3) and {256+4*lane+r} (regs 4..7);
    // z outputs {4*lane+s}.
    float h1A[8], h1B[8], h2A[8], h2B[8];
#pragma unroll
    for (int r = 0; r < 8; ++r) {
        int s = (r < 4) ? (4 * lane + r) : (256 + 4 * lane + (r - 4));
        int i = s >> 2, t = s & 3;
        int uu = (i == 127) ? (508 + t) : (127 * t + i);
        float v1 = b1[uu], v2 = b2[uu];
        h1A[r] = v1; h1B[r] = v1; h2A[r] = v2; h2B[r] = v2;
    }
    float zA[4], zB[4];
    {
        const float4 bz = *(const float4*)(b3 + 4 * lane);
        zA[0] = bz.x; zA[1] = bz.y; zA[2] = bz.z; zA[3] = bz.w;
        zB[0] = bz.x; zB[1] = bz.y; zB[2] = bz.z; zB[3] = bz.w;
    }
    const float uA0 = u[rA * 128 + lane], uA1 = u[rA * 128 + 64 + lane];
    const float uB0 = u[rB * 128 + lane], uB1 = u[rB * 128 + 64 + lane];

    float xA0 = 0.f, xA1 = 0.f, xB0 = 0.f, xB1 = 0.f, ldA = 0.f, ldB = 0.f;

    // running per-thread column pointers (advance once per LOADS)
    const float* q1  = P1 + 4 * lane;
    const float* q2a = P2 + 4 * lane;
    const float* q2b = P2 + 1024 + 4 * lane;
    const float* q3  = P3 + 4 * lane;

    DECL_WSET(wa)
    DECL_WSET(wb)

    LOADS(wa, true);                 // step 0
#pragma unroll 1
    for (int i = 0; i < 62; i += 2) {      // steps 0..61, loads 1..62 (all lo)
        LOADS(wb, true);
        STEP(i, wa, true);
        LOADS(wa, true);
        STEP(i + 1, wb, true);
    }
    // bridge: steps 62,63 (lo); loads 63 (lo), 64 (hi)
    LOADS(wb, true);
    STEP(62, wa, true);
    LOADS(wa, false);
    STEP(63, wb, true);
#pragma unroll 1
    for (int i = 64; i < 126; i += 2) {    // steps 64..125, loads 65..126 (hi)
        LOADS(wb, false);
        STEP(i, wa, false);
        LOADS(wa, false);
        STEP(i + 1, wb, false);
    }
    STEP(126, wa, false);

    // step 127: no propagation — x_127 and logdet only (mu=z[127], sg=z[255])
    {
        const float muA = rl(zA[3], 31), sgA = rl(zA[3], 63);
        const float muB = rl(zB[3], 31), sgB = rl(zB[3], 63);
        const float uiA = rl(uA1, 63), uiB = rl(uB1, 63);
        const float xiA = fmaf(uiA, __expf(sgA), muA);
        const float xiB = fmaf(uiB, __expf(sgB), muB);
        ldA += sgA; ldB += sgB;
        if (lane == 63) { xA1 = xiA; xB1 = xiB; }
    }

    out[rA * 128 + lane]      = xA0;
    out[rA * 128 + 64 + lane] = xA1;
    out[rB * 128 + lane]      = xB0;
    out[rB * 128 + 64 + lane] = xB1;
    if (lane == 0) {
        out[BATCH * 128 + rA] = ldA;
        out[BATCH * 128 + rB] = ldB;
    }
}

extern "C" void kernel_launch(void* const* d_in, const int* in_sizes, int n_in,
                              void* d_out, int out_size, void* d_ws, size_t ws_size,
                              hipStream_t stream)
{
    const float* u  = (const float*)d_in[0];
    const float* W1 = (const float*)d_in[1];
    const float* b1 = (const float*)d_in[2];
    const float* W2 = (const float*)d_in[3];
    const float* b2 = (const float*)d_in[4];
    const float* W3 = (const float*)d_in[5];
    const float* b3 = (const float*)d_in[6];
    // masks computed analytically in maf_prep; d_in[7..9] unused.
    float* ws  = (float*)d_ws;
    float* out = (float*)d_out;
    (void)ws_size; (void)in_sizes; (void)n_in; (void)out_size;

    maf_prep<<<448, 256, 0, stream>>>(W1, W2, W3, ws);
    maf_inverse<<<256, 256, 0, stream>>>(u, b1, b2, b3, ws, out);
}